// Round 1
// baseline (855.157 us; speedup 1.0000x reference)
//
#include <hip/hip_runtime.h>

// ImplicitField: B=4, C=32, G=64, N=131072, HID=128
//
// Pipeline:
//  1) k_transpose_feat: features [B,C,D,H,W] -> ft [B,D,H,W,C] in d_ws so a
//     voxel's 32 channels are one contiguous 128B line (gather-friendly).
//  2) k_transpose_w2:   w2 [j][k] -> w2t [k][j] so layer-2 inner loop reads
//     16 contiguous floats per k (merges to s_load_dwordx16).
//  3) k_field: one point per lane. Trilinear gather (8 corners x 8 float4),
//     layer1 fully unrolled (h1[128] static in VGPRs, weights via scalar
//     loads), layer2 in dynamic jc-chunks of 16 accumulators with k
//     statically unrolled, layer3 fused into the chunk epilogue.
//  points are copied to d_out via hipMemcpyAsync (D2D, graph-capture safe).

static constexpr int    kB   = 4;
static constexpr int    kN   = 131072;
static constexpr int    kG   = 64;
static constexpr int    kC   = 32;
static constexpr size_t kFtElems = (size_t)kB * kG * kG * kG * kC; // 33,554,432

__global__ __launch_bounds__(256) void k_transpose_feat(
    const float* __restrict__ f, float* __restrict__ ft)
{
    // one block per (b, z, y): transpose the [C=32][W=64] slice
    __shared__ float tile[32][65];            // +1 pad: conflict-free col reads
    const int blk = blockIdx.x;
    const int b = blk >> 12;
    const int z = (blk >> 6) & 63;
    const int y = blk & 63;
    const int t = threadIdx.x;

    // read coalesced along x
    const int x  = t & 63;
    const int c0 = t >> 6;                    // 0..3
    const size_t ibase = (size_t)b * 8388608 + (size_t)z * 4096 + (size_t)y * 64;
    #pragma unroll
    for (int cc = 0; cc < 8; ++cc) {
        const int c = c0 + cc * 4;
        tile[c][x] = f[ibase + (size_t)c * 262144 + x];
    }
    __syncthreads();

    // write coalesced along c (out is contiguous in c)
    const size_t obase = ((size_t)b * 262144 + (size_t)z * 4096 + (size_t)y * 64) * 32;
    const int c  = t & 31;
    const int x0 = t >> 5;                    // 0..7
    #pragma unroll
    for (int xo = 0; xo < 8; ++xo) {
        const int xx = x0 + xo * 8;
        ft[obase + (size_t)xx * 32 + c] = tile[c][xx];
    }
}

__global__ __launch_bounds__(256) void k_transpose_w2(
    const float* __restrict__ w2, float* __restrict__ w2t)
{
    const int i = blockIdx.x * 256 + threadIdx.x;   // 0..16383; i = k*128 + j
    w2t[i] = w2[(i & 127) * 128 + (i >> 7)];
}

__global__ __launch_bounds__(256, 2) void k_field(
    const float* __restrict__ ft, const float* __restrict__ w2t,
    const float* __restrict__ points,
    const float* __restrict__ w1, const float* __restrict__ b1,
    const float* __restrict__ b2,
    const float* __restrict__ w3, const float* __restrict__ b3,
    float* __restrict__ dens)
{
    const int g = blockIdx.x * 256 + threadIdx.x;   // 0..524287
    const int b = g >> 17;

    const float* pp = points + (size_t)g * 3;
    const float px = pp[0], py = pp[1], pz = pp[2];

    // reference: g=(p+1)/2 then pixel=((g+1)/2)*(dim-1) => (0.25p+0.75)*63
    const float fx = (0.25f * px + 0.75f) * 63.0f;
    const float fy = (0.25f * py + 0.75f) * 63.0f;
    const float fz = (0.25f * pz + 0.75f) * 63.0f;
    const float xf = floorf(fx), yf = floorf(fy), zf = floorf(fz);
    const float wx = fx - xf, wy = fy - yf, wz = fz - zf;
    int ix0 = (int)xf; ix0 = ix0 < 0 ? 0 : (ix0 > 63 ? 63 : ix0);
    int iy0 = (int)yf; iy0 = iy0 < 0 ? 0 : (iy0 > 63 ? 63 : iy0);
    int iz0 = (int)zf; iz0 = iz0 < 0 ? 0 : (iz0 > 63 ? 63 : iz0);
    const int ix1 = ix0 + 1 > 63 ? 63 : ix0 + 1;
    const int iy1 = iy0 + 1 > 63 ? 63 : iy0 + 1;
    const int iz1 = iz0 + 1 > 63 ? 63 : iz0 + 1;

    // ---- trilinear gather: 8 corners, each 32 contiguous channels ----
    float feat[32];
    #pragma unroll
    for (int c = 0; c < 32; ++c) feat[c] = 0.0f;

    const size_t vb = (size_t)b * 262144;
    #pragma unroll
    for (int corner = 0; corner < 8; ++corner) {
        const int dz = corner >> 2, dy = (corner >> 1) & 1, dx = corner & 1;
        const int iz = dz ? iz1 : iz0;
        const int iy = dy ? iy1 : iy0;
        const int ix = dx ? ix1 : ix0;
        const float w = (dz ? wz : 1.0f - wz) *
                        (dy ? wy : 1.0f - wy) *
                        (dx ? wx : 1.0f - wx);
        const float4* vp = reinterpret_cast<const float4*>(
            ft + ((vb + (size_t)iz * 4096 + (size_t)iy * 64 + (size_t)ix) << 5));
        #pragma unroll
        for (int q = 0; q < 8; ++q) {
            const float4 v = vp[q];
            feat[q * 4 + 0] = fmaf(w, v.x, feat[q * 4 + 0]);
            feat[q * 4 + 1] = fmaf(w, v.y, feat[q * 4 + 1]);
            feat[q * 4 + 2] = fmaf(w, v.z, feat[q * 4 + 2]);
            feat[q * 4 + 3] = fmaf(w, v.w, feat[q * 4 + 3]);
        }
    }

    // ---- layer 1: h1[128] = relu(W1 x + b1), fully unrolled, h1 in VGPRs ----
    float h1[128];
    #pragma unroll
    for (int j = 0; j < 128; ++j) {
        const float* wr = w1 + j * 35;        // uniform address -> s_load
        float a = b1[j];
        a = fmaf(wr[0], px, a);
        a = fmaf(wr[1], py, a);
        a = fmaf(wr[2], pz, a);
        #pragma unroll
        for (int c = 0; c < 32; ++c) a = fmaf(wr[3 + c], feat[c], a);
        h1[j] = fmaxf(a, 0.0f);
    }

    // ---- layer 2 + 3 fused: h2 chunks of 16, dot with w3 immediately ----
    float acc_out = b3[0];
    #pragma unroll 1
    for (int jc = 0; jc < 8; ++jc) {          // dynamic: keeps code ~2K instrs
        const float* wt = w2t + jc * 16;      // w2t[k][j]: 16 contiguous j per k
        float acc[16];
        #pragma unroll
        for (int jj = 0; jj < 16; ++jj) acc[jj] = b2[jc * 16 + jj];
        #pragma unroll
        for (int k = 0; k < 128; ++k) {       // static k: h1[k] stays in VGPRs
            const float h = h1[k];
            #pragma unroll
            for (int jj = 0; jj < 16; ++jj)
                acc[jj] = fmaf(wt[(size_t)k * 128 + jj], h, acc[jj]);
        }
        #pragma unroll
        for (int jj = 0; jj < 16; ++jj)
            acc_out = fmaf(w3[jc * 16 + jj], fmaxf(acc[jj], 0.0f), acc_out);
    }

    dens[g] = acc_out;
}

extern "C" void kernel_launch(void* const* d_in, const int* in_sizes, int n_in,
                              void* d_out, int out_size, void* d_ws, size_t ws_size,
                              hipStream_t stream)
{
    const float* features = (const float*)d_in[0];
    const float* points   = (const float*)d_in[1];
    const float* w1 = (const float*)d_in[2];
    const float* b1 = (const float*)d_in[3];
    const float* w2 = (const float*)d_in[4];
    const float* b2 = (const float*)d_in[5];
    const float* w3 = (const float*)d_in[6];
    const float* b3 = (const float*)d_in[7];

    float* ft  = (float*)d_ws;                                   // 128 MiB
    float* w2t = (float*)((char*)d_ws + kFtElems * sizeof(float)); // 64 KiB

    float* out_points = (float*)d_out;
    float* out_dens   = (float*)d_out + (size_t)kB * kN * 3;

    // output tuple element 0: the points, passed through
    hipMemcpyAsync(out_points, points, (size_t)kB * kN * 3 * sizeof(float),
                   hipMemcpyDeviceToDevice, stream);

    k_transpose_feat<<<16384, 256, 0, stream>>>(features, ft);
    k_transpose_w2<<<64, 256, 0, stream>>>(w2, w2t);
    k_field<<<2048, 256, 0, stream>>>(ft, w2t, points, w1, b1, b2, w3, b3, out_dens);
}